// Round 11
// baseline (283.633 us; speedup 1.0000x reference)
//
#include <hip/hip_runtime.h>
#include <hip/hip_bf16.h>

#define N_NODES 100000
#define N_EDGES 1600000
#define D 128
#define NBUCK 782           // ceil(N_NODES / 128)
#define BSTRIDE 2560        // fixed slots per bucket (avg 2046, +5 sigma safe)
#define EPB 4096            // edges per bscatter block (391 blocks)

typedef __attribute__((ext_vector_type(8))) short short8v;
typedef __attribute__((ext_vector_type(4))) float f32x4;

__device__ __forceinline__ unsigned short f2bf(float f) {
    unsigned int u = __float_as_uint(f);
    unsigned int r = (u + 0x7fffu + ((u >> 16) & 1u)) >> 16;
    return (unsigned short)r;
}
__device__ __forceinline__ float bf2f(unsigned int lo16) {
    return __uint_as_float(lo16 << 16);
}
__device__ __forceinline__ short8v zero8() {
    short8v z = {0, 0, 0, 0, 0, 0, 0, 0};
    return z;
}
// 8 f32 -> 8 bf16 via v_cvt_pk_bf16_f32
__device__ __forceinline__ short8v cvt8(const float4 p0, const float4 p1) {
    union { __hip_bfloat162 h[4]; short8v s; } u;
    u.h[0] = __float22bfloat162_rn(make_float2(p0.x, p0.y));
    u.h[1] = __float22bfloat162_rn(make_float2(p0.z, p0.w));
    u.h[2] = __float22bfloat162_rn(make_float2(p1.x, p1.y));
    u.h[3] = __float22bfloat162_rn(make_float2(p1.z, p1.w));
    return u.s;
}

// ---------------- single-pass bucket scatter (by dst>>7) ----------------
// count-pass atomic returns within-block rank; payload staged in regs (static idx);
// one global reservation atomic per (block,bucket); direct scatter. No re-reads.
__global__ __launch_bounds__(256) void k_bscatter(const int* __restrict__ src,
                                                  const int* __restrict__ dst,
                                                  int* __restrict__ gcnt,
                                                  unsigned int* __restrict__ ebuf) {
    __shared__ int cnt[NBUCK];
    __shared__ int base[NBUCK];
    const int t = threadIdx.x;
    const int e0 = blockIdx.x * EPB;
    for (int i = t; i < NBUCK; i += 256) cnt[i] = 0;
    __syncthreads();
    unsigned int pay[16];
    int meta[16];                       // (bucket<<16)|rank, or -1
#pragma unroll
    for (int u = 0; u < 16; ++u) {
        int e = e0 + u * 256 + t;
        if (e < N_EDGES) {
            int d = dst[e];
            int b = d >> 7;
            int r = atomicAdd(&cnt[b], 1);
            meta[u] = (b << 16) | r;
            pay[u] = ((unsigned int)(d & 127) << 17) | (unsigned int)src[e];
        } else meta[u] = -1;
    }
    __syncthreads();
    for (int i = t; i < NBUCK; i += 256) {
        int c = cnt[i];
        base[i] = c ? atomicAdd(&gcnt[i], c) : 0;
    }
    __syncthreads();
#pragma unroll
    for (int u = 0; u < 16; ++u) {
        if (meta[u] >= 0) {
            int b = meta[u] >> 16;
            int r = meta[u] & 0xffff;
            ebuf[b * BSTRIDE + base[b] + r] = pay[u];
        }
    }
}

// ---------------- single-pass per-bucket counting sort by local dst ----------------
__global__ __launch_bounds__(256) void k_bsort(const unsigned int* __restrict__ ebuf,
                                               const int* __restrict__ gcnt,
                                               int* __restrict__ row_start,
                                               int* __restrict__ ssrc) {
    __shared__ int h[128];
    __shared__ int sc[128];
    const int b = blockIdx.x;
    const int t = threadIdx.x;
    const int eb = b * BSTRIDE;
    const int n = gcnt[b];
    if (t < 128) h[t] = 0;
    __syncthreads();
    unsigned int pay[BSTRIDE / 256];
    int meta[BSTRIDE / 256];            // (dl<<16)|rank, or -1
#pragma unroll
    for (int u = 0; u < BSTRIDE / 256; ++u) {
        int e = t + u * 256;
        if (e < n) {
            unsigned int pk = ebuf[eb + e];
            int dl = pk >> 17;
            int r = atomicAdd(&h[dl], 1);
            meta[u] = (dl << 16) | r;
            pay[u] = pk;
        } else meta[u] = -1;
    }
    __syncthreads();
    if (t < 128) sc[t] = h[t];
    __syncthreads();
    for (int o = 1; o < 128; o <<= 1) {
        int add = 0;
        if (t < 128 && t >= o) add = sc[t - o];
        __syncthreads();
        if (t < 128) sc[t] += add;
        __syncthreads();
    }
    if (t < 128) {
        int excl = sc[t] - h[t];
        row_start[b * 129 + t] = eb + excl;
        sc[t] = excl;                   // sc becomes exclusive base
    }
    if (t == 0) row_start[b * 129 + 128] = eb + n;
    __syncthreads();
#pragma unroll
    for (int u = 0; u < BSTRIDE / 256; ++u) {
        if (meta[u] >= 0) {
            int dl = meta[u] >> 16;
            int r = meta[u] & 0xffff;
            ssrc[eb + sc[dl] + r] = (int)(pay[u] & 0x1ffffu);
        }
    }
}

// ---------------- layer-1 GEMM: [N x 128]f32 @ [128 x 256] -> t1 bf16 | h_pre bf16 ----------
// weights read as f32 + converted in-register (no prep kernel)
__global__ __launch_bounds__(256) void k_gemm1(
    const float* __restrict__ Af,            // x f32
    const float* __restrict__ W1l, const float* __restrict__ W1r,
    const float* __restrict__ bias,          // b1
    unsigned short* __restrict__ Tout,       // t1 [N][128] bf16
    unsigned short* __restrict__ Hout)       // h_pre [N][128] bf16
{
    const int wid = threadIdx.x >> 6;
    const int lane = threadIdx.x & 63;
    const int l15 = lane & 15, lg = lane >> 4;
    const int col_base = wid * 64;

    short8v bfrag[4][4];
#pragma unroll
    for (int cg = 0; cg < 4; ++cg) {
        const int row = col_base + cg * 16 + l15;              // 0..255
        const float* wrow = (row < 128) ? &W1l[(size_t)row * 128]
                                        : &W1r[(size_t)(row - 128) * 128];
#pragma unroll
        for (int ks = 0; ks < 4; ++ks) {
            const int k0 = ks * 32 + lg * 8;
            bfrag[cg][ks] = cvt8(*(const float4*)&wrow[k0],
                                 *(const float4*)&wrow[k0 + 4]);
        }
    }
    float bv[4];
#pragma unroll
    for (int cg = 0; cg < 4; ++cg)
        bv[cg] = (wid >= 2) ? bias[(wid - 2) * 64 + cg * 16 + l15] : 0.0f;

    const int row0 = blockIdx.x * 64;
    f32x4 acc[4][4];
#pragma unroll
    for (int rg = 0; rg < 4; ++rg)
#pragma unroll
        for (int cg = 0; cg < 4; ++cg)
            acc[rg][cg] = (f32x4){0.f, 0.f, 0.f, 0.f};

#pragma unroll
    for (int rg = 0; rg < 4; ++rg) {
        const int arow = row0 + rg * 16 + l15;
        short8v afrag[4];
        if (arow < N_NODES) {
#pragma unroll
            for (int ks = 0; ks < 4; ++ks)
                afrag[ks] = cvt8(*(const float4*)&Af[(size_t)arow * 128 + ks * 32 + lg * 8],
                                 *(const float4*)&Af[(size_t)arow * 128 + ks * 32 + lg * 8 + 4]);
        } else {
#pragma unroll
            for (int ks = 0; ks < 4; ++ks) afrag[ks] = zero8();
        }
#pragma unroll
        for (int cg = 0; cg < 4; ++cg)
#pragma unroll
            for (int ks = 0; ks < 4; ++ks)
                acc[rg][cg] = __builtin_amdgcn_mfma_f32_16x16x32_bf16(
                    afrag[ks], bfrag[cg][ks], acc[rg][cg], 0, 0, 0);
    }

    unsigned short* outp = (wid < 2) ? Tout : Hout;
    const int cb = (wid < 2) ? col_base : col_base - 128;
    const bool addb = (wid >= 2);
#pragma unroll
    for (int rg = 0; rg < 4; ++rg) {
        const int rbase = row0 + rg * 16 + lg * 4;
#pragma unroll
        for (int cg = 0; cg < 4; ++cg) {
            const int col = cb + cg * 16 + l15;
#pragma unroll
            for (int i = 0; i < 4; ++i) {
                int row = rbase + i;
                if (row < N_NODES) {
                    float v = acc[rg][cg][i] + (addb ? bv[cg] : 0.0f);
                    *(__hip_bfloat16*)&outp[(size_t)row * 128 + col] = __float2bfloat16(v);
                }
            }
        }
    }
}

// ---------------- layer-2 fused GEMM: out = [m2|h] @ [W2l|W2r]^T + b2  (K=256, f32 out) ----
__global__ __launch_bounds__(256) void k_gemm2(
    const unsigned short* __restrict__ M,    // m2 [N][128] bf16
    const unsigned short* __restrict__ H,    // h  [N][128] bf16
    const float* __restrict__ W2l, const float* __restrict__ W2r,
    const float* __restrict__ bias,          // b2
    float* __restrict__ out)
{
    const int wid = threadIdx.x >> 6;        // 4 waves x 32 cols
    const int lane = threadIdx.x & 63;
    const int l15 = lane & 15, lg = lane >> 4;
    const int col_base = wid * 32;

    short8v bfrag[2][8];
#pragma unroll
    for (int cg = 0; cg < 2; ++cg) {
        const int o = col_base + cg * 16 + l15;                // 0..127
        const float* wl = &W2l[(size_t)o * 128];
        const float* wr = &W2r[(size_t)o * 128];
#pragma unroll
        for (int ks = 0; ks < 4; ++ks) {
            const int k0 = ks * 32 + lg * 8;
            bfrag[cg][ks]     = cvt8(*(const float4*)&wl[k0], *(const float4*)&wl[k0 + 4]);
            bfrag[cg][ks + 4] = cvt8(*(const float4*)&wr[k0], *(const float4*)&wr[k0 + 4]);
        }
    }
    float bv[2];
#pragma unroll
    for (int cg = 0; cg < 2; ++cg)
        bv[cg] = bias[col_base + cg * 16 + l15];

    const int row0 = blockIdx.x * 64;
    f32x4 acc[4][2];
#pragma unroll
    for (int rg = 0; rg < 4; ++rg)
#pragma unroll
        for (int cg = 0; cg < 2; ++cg)
            acc[rg][cg] = (f32x4){0.f, 0.f, 0.f, 0.f};

#pragma unroll
    for (int rg = 0; rg < 4; ++rg) {
        const int arow = row0 + rg * 16 + l15;
        short8v afrag[8];
        if (arow < N_NODES) {
#pragma unroll
            for (int ks = 0; ks < 4; ++ks) {
                afrag[ks]     = *(const short8v*)&M[(size_t)arow * 128 + ks * 32 + lg * 8];
                afrag[ks + 4] = *(const short8v*)&H[(size_t)arow * 128 + ks * 32 + lg * 8];
            }
        } else {
#pragma unroll
            for (int ks = 0; ks < 8; ++ks) afrag[ks] = zero8();
        }
#pragma unroll
        for (int cg = 0; cg < 2; ++cg)
#pragma unroll
            for (int ks = 0; ks < 8; ++ks)
                acc[rg][cg] = __builtin_amdgcn_mfma_f32_16x16x32_bf16(
                    afrag[ks], bfrag[cg][ks], acc[rg][cg], 0, 0, 0);
    }

#pragma unroll
    for (int rg = 0; rg < 4; ++rg) {
        const int rbase = row0 + rg * 16 + lg * 4;
#pragma unroll
        for (int cg = 0; cg < 2; ++cg) {
            const int col = col_base + cg * 16 + l15;
#pragma unroll
            for (int i = 0; i < 4; ++i) {
                int row = rbase + i;
                if (row < N_NODES)
                    out[(size_t)row * 128 + col] = acc[rg][cg][i] + bv[cg];
            }
        }
    }
}

// ---------------- pull aggregation: wave per node, 2 edges/iter (dwordx2 lanes) ----------
template <bool RMW>
__global__ __launch_bounds__(256) void k_agg(
    const unsigned short* __restrict__ t_mat,   // gather source [N][128] bf16
    const int* __restrict__ ssrc,               // srcs sorted by dst (bucket-local CSR)
    const int* __restrict__ row_start,          // 129 per bucket
    unsigned short* __restrict__ io)            // [N][128] bf16
{
    int w = (blockIdx.x * blockDim.x + threadIdx.x) >> 6;
    int lane = threadIdx.x & 63;
    if (w >= N_NODES) return;
    const int b = w >> 7, dl = w & 127;
    const int rs = row_start[b * 129 + dl];
    const int re = row_start[b * 129 + dl + 1];
    const int d = re - rs;
    const int half = lane >> 5;
    const int l31 = lane & 31;

    uint2 cur;
    cur.x = 0u; cur.y = 0u;
    if (RMW && lane < 32)
        cur = *((const uint2*)io + (size_t)w * 32 + l31);

    const uint2* tlane = (const uint2*)t_mat + l31;   // + j*32 per row
    float a0 = 0.f, a1 = 0.f, a2 = 0.f, a3 = 0.f;

    for (int q0 = rs; q0 < re; q0 += 64) {
        int nb = 0;
        if (q0 + lane < re) nb = ssrc[q0 + lane];
        const int m = min(64, re - q0);
        int q = 0;
        for (; q + 16 <= m; q += 16) {      // 16 edges per step, 8 loads in flight
            uint2 v[8];
#pragma unroll
            for (int u = 0; u < 8; ++u) {
                int j = __shfl(nb, q + u * 2 + half);
                v[u] = tlane[(size_t)j * 32];
            }
#pragma unroll
            for (int u = 0; u < 8; ++u) {
                a0 += bf2f(v[u].x & 0xffffu);
                a1 += __uint_as_float(v[u].x & 0xffff0000u);
                a2 += bf2f(v[u].y & 0xffffu);
                a3 += __uint_as_float(v[u].y & 0xffff0000u);
            }
        }
        for (; q + 2 <= m; q += 2) {
            int j = __shfl(nb, q + half);
            uint2 vv = tlane[(size_t)j * 32];
            a0 += bf2f(vv.x & 0xffffu);
            a1 += __uint_as_float(vv.x & 0xffff0000u);
            a2 += bf2f(vv.y & 0xffffu);
            a3 += __uint_as_float(vv.y & 0xffff0000u);
        }
        if (q < m) {                        // odd tail edge: half 0 only
            int j = __shfl(nb, q);
            if (half == 0) {
                uint2 vv = tlane[(size_t)j * 32];
                a0 += bf2f(vv.x & 0xffffu);
                a1 += __uint_as_float(vv.x & 0xffff0000u);
                a2 += bf2f(vv.y & 0xffffu);
                a3 += __uint_as_float(vv.y & 0xffff0000u);
            }
        }
    }

    a0 += __shfl_xor(a0, 32);
    a1 += __shfl_xor(a1, 32);
    a2 += __shfl_xor(a2, 32);
    a3 += __shfl_xor(a3, 32);

    if (lane < 32) {
        const float inv = 1.0f / (float)max(d, 1);
        float r0, r1, r2, r3;
        if (RMW) {
            r0 = fmaxf(bf2f(cur.x & 0xffffu) + inv * a0, 0.f);
            r1 = fmaxf(__uint_as_float(cur.x & 0xffff0000u) + inv * a1, 0.f);
            r2 = fmaxf(bf2f(cur.y & 0xffffu) + inv * a2, 0.f);
            r3 = fmaxf(__uint_as_float(cur.y & 0xffff0000u) + inv * a3, 0.f);
        } else {
            r0 = inv * a0; r1 = inv * a1; r2 = inv * a2; r3 = inv * a3;
        }
        uint2 o;
        o.x = (unsigned int)f2bf(r0) | ((unsigned int)f2bf(r1) << 16);
        o.y = (unsigned int)f2bf(r2) | ((unsigned int)f2bf(r3) << 16);
        *((uint2*)io + (size_t)w * 32 + l31) = o;
    }
}

// ---------------- launch ----------------

extern "C" void kernel_launch(void* const* d_in, const int* in_sizes, int n_in,
                              void* d_out, int out_size, void* d_ws, size_t ws_size,
                              hipStream_t stream) {
    const float* x   = (const float*)d_in[0];
    const int*   ei  = (const int*)d_in[1];
    const float* W1l = (const float*)d_in[2];
    const float* W1r = (const float*)d_in[3];
    const float* b1  = (const float*)d_in[4];
    const float* W2l = (const float*)d_in[5];
    const float* W2r = (const float*)d_in[6];
    const float* b2  = (const float*)d_in[7];
    float* out = (float*)d_out;

    const int* src = ei;
    const int* dst = ei + N_EDGES;

    char* p = (char*)d_ws;
    auto alloc = [&](size_t bytes) {
        char* r = p;
        p += (bytes + 255) & ~(size_t)255;
        return r;
    };
    unsigned short* tb = (unsigned short*)alloc((size_t)N_NODES * D * 2);   // t1 / m2
    unsigned short* hx = (unsigned short*)alloc((size_t)N_NODES * D * 2);   // h
    unsigned int*   ebuf = (unsigned int*)alloc((size_t)NBUCK * BSTRIDE * 4); // 8MB
    int*   ssrc      = (int*)alloc((size_t)NBUCK * BSTRIDE * 4);              // 8MB
    int*   gcnt      = (int*)alloc(NBUCK * sizeof(int));
    int*   row_start = (int*)alloc((size_t)NBUCK * 129 * sizeof(int));

    const int g1_tiles = (N_NODES + 63) / 64;   // 1563
    const int agg_grid = (N_NODES + 3) / 4;

    hipMemsetAsync(gcnt, 0, NBUCK * sizeof(int), stream);
    k_bscatter<<<(N_EDGES + EPB - 1) / EPB, 256, 0, stream>>>(src, dst, gcnt, ebuf);
    k_bsort<<<NBUCK, 256, 0, stream>>>(ebuf, gcnt, row_start, ssrc);

    // layer 1: [t1|h_pre] = x @ [W1l;W1r]^T (+b1); h = relu(h_pre + mean t1[nbrs])
    k_gemm1<<<g1_tiles, 256, 0, stream>>>(x, W1l, W1r, b1, tb, hx);
    k_agg<true><<<agg_grid, 256, 0, stream>>>(tb, ssrc, row_start, hx);

    // layer 2: m2 = mean h[nbrs]; out = [m2|h] @ [W2l|W2r]^T + b2
    k_agg<false><<<agg_grid, 256, 0, stream>>>(hx, ssrc, row_start, tb);
    k_gemm2<<<g1_tiles, 256, 0, stream>>>(tb, hx, W2l, W2r, b2, out);
}

// Round 12
// 247.525 us; speedup vs baseline: 1.1459x; 1.1459x over previous
//
#include <hip/hip_runtime.h>
#include <hip/hip_bf16.h>

#define N_NODES 100000
#define N_EDGES 1600000
#define D 128
#define NBUCK 782           // ceil(N_NODES / 128)
#define BSTRIDE 2560        // fixed slots per bucket (avg 2046, +5 sigma safe)
#define EPB 4096            // edges per bscatter block (391 blocks)

typedef __attribute__((ext_vector_type(8))) short short8v;
typedef __attribute__((ext_vector_type(4))) float f32x4;

__device__ __forceinline__ unsigned short f2bf(float f) {
    unsigned int u = __float_as_uint(f);
    unsigned int r = (u + 0x7fffu + ((u >> 16) & 1u)) >> 16;
    return (unsigned short)r;
}
__device__ __forceinline__ float bf2f(unsigned int lo16) {
    return __uint_as_float(lo16 << 16);
}
__device__ __forceinline__ short8v zero8() {
    short8v z = {0, 0, 0, 0, 0, 0, 0, 0};
    return z;
}
// 8 f32 -> 8 bf16 via v_cvt_pk_bf16_f32
__device__ __forceinline__ short8v cvt8(const float4 p0, const float4 p1) {
    union { __hip_bfloat162 h[4]; short8v s; } u;
    u.h[0] = __float22bfloat162_rn(make_float2(p0.x, p0.y));
    u.h[1] = __float22bfloat162_rn(make_float2(p0.z, p0.w));
    u.h[2] = __float22bfloat162_rn(make_float2(p1.x, p1.y));
    u.h[3] = __float22bfloat162_rn(make_float2(p1.z, p1.w));
    return u.s;
}

// ---------------- prep: pack weights bf16 (once), zero bucket cursors ----------------
// wc1: [256][128]  rows 0..127 = W1l, 128..255 = W1r
// wc2: [128][256]  row o, cols 0..127 = W2l[o][k], 128..255 = W2r[o][k-128]
__global__ void k_prep(const float* __restrict__ W1l, const float* __restrict__ W1r,
                       const float* __restrict__ W2l, const float* __restrict__ W2r,
                       unsigned short* __restrict__ wc1, unsigned short* __restrict__ wc2,
                       int* __restrict__ gcnt) {
    int idx = blockIdx.x * 256 + threadIdx.x;
    if (idx < 16384)       wc1[idx] = f2bf(W1l[idx]);
    else if (idx < 32768)  wc1[idx] = f2bf(W1r[idx - 16384]);
    else if (idx < 65536) {
        int j = idx - 32768;
        int o = j >> 8, k2 = j & 255;
        float v = (k2 < 128) ? W2l[o * 128 + k2] : W2r[o * 128 + (k2 - 128)];
        wc2[j] = f2bf(v);
    }
    else if (idx - 65536 < NBUCK) gcnt[idx - 65536] = 0;
}

// ---------------- single-pass bucket scatter (by dst>>7) ----------------
__global__ __launch_bounds__(256) void k_bscatter(const int* __restrict__ src,
                                                  const int* __restrict__ dst,
                                                  int* __restrict__ gcnt,
                                                  unsigned int* __restrict__ ebuf) {
    __shared__ int cnt[NBUCK];
    __shared__ int base[NBUCK];
    const int t = threadIdx.x;
    const int e0 = blockIdx.x * EPB;
    for (int i = t; i < NBUCK; i += 256) cnt[i] = 0;
    __syncthreads();
    unsigned int pay[16];
    int meta[16];                       // (bucket<<16)|rank, or -1
#pragma unroll
    for (int u = 0; u < 16; ++u) {
        int e = e0 + u * 256 + t;
        if (e < N_EDGES) {
            int d = dst[e];
            int b = d >> 7;
            int r = atomicAdd(&cnt[b], 1);
            meta[u] = (b << 16) | r;
            pay[u] = ((unsigned int)(d & 127) << 17) | (unsigned int)src[e];
        } else meta[u] = -1;
    }
    __syncthreads();
    for (int i = t; i < NBUCK; i += 256) {
        int c = cnt[i];
        base[i] = c ? atomicAdd(&gcnt[i], c) : 0;
    }
    __syncthreads();
#pragma unroll
    for (int u = 0; u < 16; ++u) {
        if (meta[u] >= 0) {
            int b = meta[u] >> 16;
            int r = meta[u] & 0xffff;
            ebuf[b * BSTRIDE + base[b] + r] = pay[u];
        }
    }
}

// ---------------- single-pass per-bucket counting sort by local dst ----------------
__global__ __launch_bounds__(256) void k_bsort(const unsigned int* __restrict__ ebuf,
                                               const int* __restrict__ gcnt,
                                               int* __restrict__ row_start,
                                               int* __restrict__ ssrc) {
    __shared__ int h[128];
    __shared__ int sc[128];
    const int b = blockIdx.x;
    const int t = threadIdx.x;
    const int eb = b * BSTRIDE;
    const int n = gcnt[b];
    if (t < 128) h[t] = 0;
    __syncthreads();
    unsigned int pay[BSTRIDE / 256];
    int meta[BSTRIDE / 256];            // (dl<<16)|rank, or -1
#pragma unroll
    for (int u = 0; u < BSTRIDE / 256; ++u) {
        int e = t + u * 256;
        if (e < n) {
            unsigned int pk = ebuf[eb + e];
            int dl = pk >> 17;
            int r = atomicAdd(&h[dl], 1);
            meta[u] = (dl << 16) | r;
            pay[u] = pk;
        } else meta[u] = -1;
    }
    __syncthreads();
    if (t < 128) sc[t] = h[t];
    __syncthreads();
    for (int o = 1; o < 128; o <<= 1) {
        int add = 0;
        if (t < 128 && t >= o) add = sc[t - o];
        __syncthreads();
        if (t < 128) sc[t] += add;
        __syncthreads();
    }
    if (t < 128) {
        int excl = sc[t] - h[t];
        row_start[b * 129 + t] = eb + excl;
        sc[t] = excl;                   // sc becomes exclusive base
    }
    if (t == 0) row_start[b * 129 + 128] = eb + n;
    __syncthreads();
#pragma unroll
    for (int u = 0; u < BSTRIDE / 256; ++u) {
        if (meta[u] >= 0) {
            int dl = meta[u] >> 16;
            int r = meta[u] & 0xffff;
            ssrc[eb + sc[dl] + r] = (int)(pay[u] & 0x1ffffu);
        }
    }
}

// ---------------- layer-1 GEMM: [N x 128]f32 @ wc1^T -> t1 bf16 | h_pre bf16 ----------
// grid-stride 640 blocks: weight-fragment prologue amortized over ~2.4 tiles
__global__ __launch_bounds__(256) void k_gemm1(
    const float* __restrict__ Af,            // x f32
    const unsigned short* __restrict__ Bt,   // wc1 [256][128] bf16
    const float* __restrict__ bias,          // b1
    unsigned short* __restrict__ Tout,       // t1 [N][128] bf16
    unsigned short* __restrict__ Hout)       // h_pre [N][128] bf16
{
    const int wid = threadIdx.x >> 6;
    const int lane = threadIdx.x & 63;
    const int l15 = lane & 15, lg = lane >> 4;
    const int col_base = wid * 64;

    short8v bfrag[4][4];
#pragma unroll
    for (int cg = 0; cg < 4; ++cg)
#pragma unroll
        for (int ks = 0; ks < 4; ++ks)
            bfrag[cg][ks] = *(const short8v*)&Bt[(size_t)(col_base + cg * 16 + l15) * 128
                                                 + ks * 32 + lg * 8];
    float bv[4];
#pragma unroll
    for (int cg = 0; cg < 4; ++cg)
        bv[cg] = (wid >= 2) ? bias[(wid - 2) * 64 + cg * 16 + l15] : 0.0f;

    const int ntiles = (N_NODES + 63) / 64;
    for (int tile = blockIdx.x; tile < ntiles; tile += gridDim.x) {
        const int row0 = tile * 64;
        f32x4 acc[4][4];
#pragma unroll
        for (int rg = 0; rg < 4; ++rg)
#pragma unroll
            for (int cg = 0; cg < 4; ++cg)
                acc[rg][cg] = (f32x4){0.f, 0.f, 0.f, 0.f};

#pragma unroll
        for (int rg = 0; rg < 4; ++rg) {
            const int arow = row0 + rg * 16 + l15;
            short8v afrag[4];
            if (arow < N_NODES) {
#pragma unroll
                for (int ks = 0; ks < 4; ++ks)
                    afrag[ks] = cvt8(*(const float4*)&Af[(size_t)arow * 128 + ks * 32 + lg * 8],
                                     *(const float4*)&Af[(size_t)arow * 128 + ks * 32 + lg * 8 + 4]);
            } else {
#pragma unroll
                for (int ks = 0; ks < 4; ++ks) afrag[ks] = zero8();
            }
#pragma unroll
            for (int cg = 0; cg < 4; ++cg)
#pragma unroll
                for (int ks = 0; ks < 4; ++ks)
                    acc[rg][cg] = __builtin_amdgcn_mfma_f32_16x16x32_bf16(
                        afrag[ks], bfrag[cg][ks], acc[rg][cg], 0, 0, 0);
        }

        unsigned short* outp = (wid < 2) ? Tout : Hout;
        const int cb = (wid < 2) ? col_base : col_base - 128;
        const bool addb = (wid >= 2);
#pragma unroll
        for (int rg = 0; rg < 4; ++rg) {
            const int rbase = row0 + rg * 16 + lg * 4;
#pragma unroll
            for (int cg = 0; cg < 4; ++cg) {
                const int col = cb + cg * 16 + l15;
#pragma unroll
                for (int i = 0; i < 4; ++i) {
                    int row = rbase + i;
                    if (row < N_NODES) {
                        float v = acc[rg][cg][i] + (addb ? bv[cg] : 0.0f);
                        outp[(size_t)row * 128 + col] = f2bf(v);
                    }
                }
            }
        }
    }
}

// ---------------- layer-2 fused GEMM: out = [m2|h] @ wc2^T + b2  (K=256, f32 out) -------
__global__ __launch_bounds__(256) void k_gemm2(
    const unsigned short* __restrict__ M,    // m2 [N][128] bf16
    const unsigned short* __restrict__ H,    // h  [N][128] bf16
    const unsigned short* __restrict__ Bt,   // wc2 [128][256] bf16
    const float* __restrict__ bias,          // b2
    float* __restrict__ out)
{
    const int wid = threadIdx.x >> 6;        // 4 waves x 32 cols
    const int lane = threadIdx.x & 63;
    const int l15 = lane & 15, lg = lane >> 4;
    const int col_base = wid * 32;

    short8v bfrag[2][8];
#pragma unroll
    for (int cg = 0; cg < 2; ++cg)
#pragma unroll
        for (int ks = 0; ks < 8; ++ks)
            bfrag[cg][ks] = *(const short8v*)&Bt[(size_t)(col_base + cg * 16 + l15) * 256
                                                 + ks * 32 + lg * 8];
    float bv[2];
#pragma unroll
    for (int cg = 0; cg < 2; ++cg)
        bv[cg] = bias[col_base + cg * 16 + l15];

    const int ntiles = (N_NODES + 63) / 64;
    for (int tile = blockIdx.x; tile < ntiles; tile += gridDim.x) {
        const int row0 = tile * 64;
        f32x4 acc[4][2];
#pragma unroll
        for (int rg = 0; rg < 4; ++rg)
#pragma unroll
            for (int cg = 0; cg < 2; ++cg)
                acc[rg][cg] = (f32x4){0.f, 0.f, 0.f, 0.f};

#pragma unroll
        for (int rg = 0; rg < 4; ++rg) {
            const int arow = row0 + rg * 16 + l15;
            short8v afrag[8];
            if (arow < N_NODES) {
#pragma unroll
                for (int ks = 0; ks < 4; ++ks) {
                    afrag[ks]     = *(const short8v*)&M[(size_t)arow * 128 + ks * 32 + lg * 8];
                    afrag[ks + 4] = *(const short8v*)&H[(size_t)arow * 128 + ks * 32 + lg * 8];
                }
            } else {
#pragma unroll
                for (int ks = 0; ks < 8; ++ks) afrag[ks] = zero8();
            }
#pragma unroll
            for (int cg = 0; cg < 2; ++cg)
#pragma unroll
                for (int ks = 0; ks < 8; ++ks)
                    acc[rg][cg] = __builtin_amdgcn_mfma_f32_16x16x32_bf16(
                        afrag[ks], bfrag[cg][ks], acc[rg][cg], 0, 0, 0);
        }

#pragma unroll
        for (int rg = 0; rg < 4; ++rg) {
            const int rbase = row0 + rg * 16 + lg * 4;
#pragma unroll
            for (int cg = 0; cg < 2; ++cg) {
                const int col = col_base + cg * 16 + l15;
#pragma unroll
                for (int i = 0; i < 4; ++i) {
                    int row = rbase + i;
                    if (row < N_NODES)
                        out[(size_t)row * 128 + col] = acc[rg][cg][i] + bv[cg];
                }
            }
        }
    }
}

// ---------------- pull aggregation: wave per node, 2 edges/iter (dwordx2 lanes) ----------
template <bool RMW>
__global__ __launch_bounds__(256) void k_agg(
    const unsigned short* __restrict__ t_mat,   // gather source [N][128] bf16
    const int* __restrict__ ssrc,               // srcs sorted by dst (bucket-local CSR)
    const int* __restrict__ row_start,          // 129 per bucket
    unsigned short* __restrict__ io)            // [N][128] bf16
{
    int w = (blockIdx.x * blockDim.x + threadIdx.x) >> 6;
    int lane = threadIdx.x & 63;
    if (w >= N_NODES) return;
    const int b = w >> 7, dl = w & 127;
    const int rs = row_start[b * 129 + dl];
    const int re = row_start[b * 129 + dl + 1];
    const int d = re - rs;
    const int half = lane >> 5;
    const int l31 = lane & 31;

    uint2 cur;
    cur.x = 0u; cur.y = 0u;
    if (RMW && lane < 32)
        cur = *((const uint2*)io + (size_t)w * 32 + l31);

    const uint2* tlane = (const uint2*)t_mat + l31;   // + j*32 per row
    float a0 = 0.f, a1 = 0.f, a2 = 0.f, a3 = 0.f;

    for (int q0 = rs; q0 < re; q0 += 64) {
        int nb = 0;
        if (q0 + lane < re) nb = ssrc[q0 + lane];
        const int m = min(64, re - q0);
        int q = 0;
        for (; q + 16 <= m; q += 16) {      // 16 edges per step, 8 loads in flight
            uint2 v[8];
#pragma unroll
            for (int u = 0; u < 8; ++u) {
                int j = __shfl(nb, q + u * 2 + half);
                v[u] = tlane[(size_t)j * 32];
            }
#pragma unroll
            for (int u = 0; u < 8; ++u) {
                a0 += bf2f(v[u].x & 0xffffu);
                a1 += __uint_as_float(v[u].x & 0xffff0000u);
                a2 += bf2f(v[u].y & 0xffffu);
                a3 += __uint_as_float(v[u].y & 0xffff0000u);
            }
        }
        for (; q + 2 <= m; q += 2) {
            int j = __shfl(nb, q + half);
            uint2 vv = tlane[(size_t)j * 32];
            a0 += bf2f(vv.x & 0xffffu);
            a1 += __uint_as_float(vv.x & 0xffff0000u);
            a2 += bf2f(vv.y & 0xffffu);
            a3 += __uint_as_float(vv.y & 0xffff0000u);
        }
        if (q < m) {                        // odd tail edge: half 0 only
            int j = __shfl(nb, q);
            if (half == 0) {
                uint2 vv = tlane[(size_t)j * 32];
                a0 += bf2f(vv.x & 0xffffu);
                a1 += __uint_as_float(vv.x & 0xffff0000u);
                a2 += bf2f(vv.y & 0xffffu);
                a3 += __uint_as_float(vv.y & 0xffff0000u);
            }
        }
    }

    a0 += __shfl_xor(a0, 32);
    a1 += __shfl_xor(a1, 32);
    a2 += __shfl_xor(a2, 32);
    a3 += __shfl_xor(a3, 32);

    if (lane < 32) {
        const float inv = 1.0f / (float)max(d, 1);
        float r0, r1, r2, r3;
        if (RMW) {
            r0 = fmaxf(bf2f(cur.x & 0xffffu) + inv * a0, 0.f);
            r1 = fmaxf(__uint_as_float(cur.x & 0xffff0000u) + inv * a1, 0.f);
            r2 = fmaxf(bf2f(cur.y & 0xffffu) + inv * a2, 0.f);
            r3 = fmaxf(__uint_as_float(cur.y & 0xffff0000u) + inv * a3, 0.f);
        } else {
            r0 = inv * a0; r1 = inv * a1; r2 = inv * a2; r3 = inv * a3;
        }
        uint2 o;
        o.x = (unsigned int)f2bf(r0) | ((unsigned int)f2bf(r1) << 16);
        o.y = (unsigned int)f2bf(r2) | ((unsigned int)f2bf(r3) << 16);
        *((uint2*)io + (size_t)w * 32 + l31) = o;
    }
}

// ---------------- launch ----------------

extern "C" void kernel_launch(void* const* d_in, const int* in_sizes, int n_in,
                              void* d_out, int out_size, void* d_ws, size_t ws_size,
                              hipStream_t stream) {
    const float* x   = (const float*)d_in[0];
    const int*   ei  = (const int*)d_in[1];
    const float* W1l = (const float*)d_in[2];
    const float* W1r = (const float*)d_in[3];
    const float* b1  = (const float*)d_in[4];
    const float* W2l = (const float*)d_in[5];
    const float* W2r = (const float*)d_in[6];
    const float* b2  = (const float*)d_in[7];
    float* out = (float*)d_out;

    const int* src = ei;
    const int* dst = ei + N_EDGES;

    char* p = (char*)d_ws;
    auto alloc = [&](size_t bytes) {
        char* r = p;
        p += (bytes + 255) & ~(size_t)255;
        return r;
    };
    unsigned short* tb = (unsigned short*)alloc((size_t)N_NODES * D * 2);   // t1 / m2
    unsigned short* hx = (unsigned short*)alloc((size_t)N_NODES * D * 2);   // h
    unsigned int*   ebuf = (unsigned int*)alloc((size_t)NBUCK * BSTRIDE * 4); // 8MB
    int*   ssrc      = (int*)alloc((size_t)NBUCK * BSTRIDE * 4);              // 8MB
    int*   gcnt      = (int*)alloc(NBUCK * sizeof(int));
    int*   row_start = (int*)alloc((size_t)NBUCK * 129 * sizeof(int));
    unsigned short* wc1 = (unsigned short*)alloc(256 * 128 * 2);
    unsigned short* wc2 = (unsigned short*)alloc(128 * 256 * 2);

    const int agg_grid = (N_NODES + 3) / 4;

    // prep (weights + cursor zero) -> single-pass scatter -> single-pass sort
    k_prep<<<(65536 + NBUCK + 255) / 256, 256, 0, stream>>>(W1l, W1r, W2l, W2r, wc1, wc2, gcnt);
    k_bscatter<<<(N_EDGES + EPB - 1) / EPB, 256, 0, stream>>>(src, dst, gcnt, ebuf);
    k_bsort<<<NBUCK, 256, 0, stream>>>(ebuf, gcnt, row_start, ssrc);

    // layer 1: [t1|h_pre] = x @ [W1l;W1r]^T (+b1); h = relu(h_pre + mean t1[nbrs])
    k_gemm1<<<640, 256, 0, stream>>>(x, wc1, b1, tb, hx);
    k_agg<true><<<agg_grid, 256, 0, stream>>>(tb, ssrc, row_start, hx);

    // layer 2: m2 = mean h[nbrs]; out = [m2|h] @ [W2l|W2r]^T + b2
    k_agg<false><<<agg_grid, 256, 0, stream>>>(hx, ssrc, row_start, tb);
    k_gemm2<<<640, 256, 0, stream>>>(tb, hx, wc2, b2, out);
}